// Round 21
// baseline (689.258 us; speedup 1.0000x reference)
//
#include <hip/hip_runtime.h>

#define D 64
#define LAYERS 3

typedef float  f4  __attribute__((ext_vector_type(4)));
typedef short  s8v __attribute__((ext_vector_type(8)));
typedef short  s4v __attribute__((ext_vector_type(4)));
typedef unsigned short ushort_t;

__device__ __forceinline__ unsigned short f2bf(float x) {
    unsigned int u = __float_as_uint(x);
    unsigned int r = (u + 0x7fffu + ((u >> 16) & 1u)) >> 16;
    return (unsigned short)r;
}
__device__ __forceinline__ float bf2f(unsigned short h) {
    return __uint_as_float(((unsigned int)h) << 16);
}

// ---------------- CSR build ----------------

__global__ void k_count(const int* __restrict__ dst, int* __restrict__ cnt, int E) {
    int e = blockIdx.x * blockDim.x + threadIdx.x;
    if (e < E) atomicAdd(&cnt[dst[e]], 1);
}

__global__ __launch_bounds__(1024) void k_scan(const int* __restrict__ cnt,
                                               int* __restrict__ row_start,
                                               float* __restrict__ inv_deg, int N) {
    __shared__ int buf[1024];
    int tid = threadIdx.x;
    int per = (N + 1023) >> 10;
    int begin = tid * per;
    int end = min(begin + per, N);
    int s = 0;
    for (int i = begin; i < end; i++) s += cnt[i];
    buf[tid] = s;
    __syncthreads();
    for (int off = 1; off < 1024; off <<= 1) {
        int v = 0;
        if (tid >= off) v = buf[tid - off];
        __syncthreads();
        buf[tid] += v;
        __syncthreads();
    }
    int run = buf[tid] - s;
    for (int i = begin; i < end; i++) {
        row_start[i] = run;
        int c = cnt[i];
        inv_deg[i] = 1.0f / (float)(c > 1 ? c : 1);
        run += c;
    }
    if (begin < N && end == N) row_start[N] = run;
}

// light fill: indices only (row-copy fusion measured -76us WORSE in R16).
__global__ void k_fill(const int* __restrict__ src, const int* __restrict__ dst,
                       const int* __restrict__ row_start, int* __restrict__ cursor,
                       int* __restrict__ eids, int* __restrict__ srcs,
                       int* __restrict__ pdst, int* __restrict__ pos, int E) {
    int e = blockIdx.x * blockDim.x + threadIdx.x;
    if (e >= E) return;
    int d = dst[e];
    int p = row_start[d] + atomicAdd(&cursor[d], 1);
    eids[p] = e;
    srcs[p] = src[e];
    pdst[p] = d;
    pos[e] = p;
}

// ---------------- fused: permute ea0 -> pea (bf16, p-order) AND x0 -> xb (bf16) ----------------
__global__ __launch_bounds__(256) void k_permcvt(const float* __restrict__ ea,
                                                 const int* __restrict__ pos,
                                                 ushort_t* __restrict__ pea, int E,
                                                 const float* __restrict__ x,
                                                 ushort_t* __restrict__ xb, int xtotal8,
                                                 int pblocks) {
    if ((int)blockIdx.x < pblocks) {
        int t = blockIdx.x * blockDim.x + threadIdx.x;
        int e = t >> 3;
        if (e >= E) return;
        int seg = t & 7;
        const float* rp = ea + (size_t)e * D + seg * 8;
        f4 a0 = *(const f4*)rp;
        f4 a1 = *(const f4*)(rp + 4);
        s8v o;
        #pragma unroll
        for (int i = 0; i < 4; i++) {
            o[i]     = (short)f2bf(a0[i]);
            o[4 + i] = (short)f2bf(a1[i]);
        }
        int p = pos[e];
        *(s8v*)(pea + (size_t)p * D + seg * 8) = o;
    } else {
        int t = (blockIdx.x - pblocks) * blockDim.x + threadIdx.x;
        if (t >= xtotal8) return;
        const float* rp = x + (size_t)t * 8;
        f4 a0 = *(const f4*)rp;
        f4 a1 = *(const f4*)(rp + 4);
        s8v o;
        #pragma unroll
        for (int i = 0; i < 4; i++) {
            o[i]     = (short)f2bf(a0[i]);
            o[4 + i] = (short)f2bf(a1[i]);
        }
        *(s8v*)(xb + (size_t)t * 8) = o;
    }
}

// ---------------- prepack ALL weight fragments (per-lane layout) ----------------
__global__ __launch_bounds__(64) void k_prepw(const float* __restrict__ Wr,
                                              const float* __restrict__ Wn,
                                              const float* __restrict__ Wec,
                                              const float* __restrict__ EWe,
                                              const float* __restrict__ EW1,
                                              const float* __restrict__ EWs,
                                              const float* __restrict__ EWt,
                                              s8v* __restrict__ wbuf) {
    int set = blockIdx.x;
    const float* Wsrc;
    int order, part;   // order: 0=natural,1=pi ; part: 0=hi,1=lo,2=single
    if (set < 18) {
        int i = set / 6, r = set % 6, m = r >> 1;
        part = r & 1;
        order = 0;
        const float* base = (m == 0) ? Wr : (m == 1) ? Wn : Wec;
        Wsrc = base + (size_t)i * D * D;
    } else if (set < 24) {
        int j = (set - 18) / 3, r = (set - 18) % 3;
        if (r == 2) { Wsrc = EW1 + (size_t)j * D * D; part = 2; order = 1; }
        else        { Wsrc = EWe + (size_t)j * D * D; part = r; order = 0; }
    } else {
        int j = (set - 24) / 2, r = (set - 24) % 2;
        Wsrc = ((r == 0) ? EWs : EWt) + (size_t)j * D * D;
        part = 2; order = 1;
    }
    int lane = threadIdx.x;
    int c = lane & 15, g = lane >> 4;
    s8v* wb = wbuf + (size_t)set * 512;
    #pragma unroll
    for (int nt = 0; nt < 4; nt++) {
        #pragma unroll
        for (int kt = 0; kt < 2; kt++) {
            s8v frag;
            #pragma unroll
            for (int i = 0; i < 8; i++) {
                int k = (order == 0) ? (32 * kt + 8 * g + i)
                                     : (32 * kt + 16 * (i >> 2) + 4 * g + (i & 3));
                float w = Wsrc[k * D + 16 * nt + c];
                unsigned short hb = f2bf(w);
                frag[i] = (part == 1) ? (short)f2bf(w - bf2f(hb)) : (short)hb;
            }
            wb[(nt * 2 + kt) * 64 + lane] = frag;
        }
    }
}

// ---------------- aggregation, vectorized + LDS-throttled occupancy ----------------
// Wave per node; lane = (row-slot r=l>>3, octet o=l&7); 16B loads, 8 rows in flight.
// R21: 40KB dummy LDS caps residency at 4 blocks/CU (16 waves/CU, ~50% occ) — the
// xb[src] gather (6.4MB array, 16x reuse/row) is L2-locality-bound like the edge
// kernel's sf gather (R4/R9/R10 mechanism); full occupancy thrashes the reuse window.
// NOTE (R18): ILP-2/16-row restructuring measured WORSE — keep simple 8-row loop.
__global__ __launch_bounds__(256) void k_agg_seq(const ushort_t* __restrict__ xb,
                                                 const ushort_t* __restrict__ pea,
                                                 const int* __restrict__ row_start,
                                                 const int* __restrict__ srcs,
                                                 ushort_t* __restrict__ Sx, ushort_t* __restrict__ Se,
                                                 int N, int keep_lds) {
    __shared__ float throttle[10240];   // 40KB -> 4 blocks/CU occupancy cap
    if (keep_lds) {                     // never true at runtime; defeats LDS elision
        throttle[threadIdx.x] = (float)threadIdx.y;
        __syncthreads();
        if (throttle[0] == 12345.f) Sx[0] = 0;
    }
    int n = blockIdx.x * 4 + threadIdx.y;
    if (n >= N) return;
    int lane = threadIdx.x;
    int r = lane >> 3;       // row slot 0..7
    int o = lane & 7;        // feature octet
    int p0 = row_start[n], p1 = row_start[n + 1];
    f4 ax0 = (f4){0.f, 0.f, 0.f, 0.f}, ax1 = (f4){0.f, 0.f, 0.f, 0.f};
    f4 ae0 = (f4){0.f, 0.f, 0.f, 0.f}, ae1 = (f4){0.f, 0.f, 0.f, 0.f};
    for (int p = p0 + r; p < p1; p += 8) {
        s8v ev = *(const s8v*)(pea + (size_t)p * D + o * 8);
        int sidx = srcs[p];
        s8v xv = *(const s8v*)(xb + (size_t)sidx * D + o * 8);
        #pragma unroll
        for (int i = 0; i < 4; i++) {
            ae0[i] += bf2f((ushort_t)ev[i]);
            ae1[i] += bf2f((ushort_t)ev[4 + i]);
            ax0[i] += bf2f((ushort_t)xv[i]);
            ax1[i] += bf2f((ushort_t)xv[4 + i]);
        }
    }
    #pragma unroll
    for (int off = 8; off < 64; off <<= 1) {
        #pragma unroll
        for (int i = 0; i < 4; i++) {
            ax0[i] += __shfl_xor(ax0[i], off);
            ax1[i] += __shfl_xor(ax1[i], off);
            ae0[i] += __shfl_xor(ae0[i], off);
            ae1[i] += __shfl_xor(ae1[i], off);
        }
    }
    if (r == 0) {
        s8v sx, se;
        #pragma unroll
        for (int i = 0; i < 4; i++) {
            sx[i]     = (short)f2bf(ax0[i]);
            sx[4 + i] = (short)f2bf(ax1[i]);
            se[i]     = (short)f2bf(ae0[i]);
            se[4 + i] = (short)f2bf(ae1[i]);
        }
        *(s8v*)(Sx + (size_t)n * D + o * 8) = sx;
        *(s8v*)(Se + (size_t)n * D + o * 8) = se;
    }
}

// ---------------- fused node update + s/t features via MFMA (zero LDS) ----------------
template<int DO_ST, int LAST>
__global__ __launch_bounds__(256) void k_node_mfma(
        const ushort_t* __restrict__ xb_in,
        const ushort_t* __restrict__ Sx, const ushort_t* __restrict__ Se,
        const float* __restrict__ inv_deg,
        const s8v* __restrict__ wbn,     // 6 sets: Wr_hi,Wr_lo,Wn_hi,Wn_lo,We_hi,We_lo
        const float* __restrict__ bias,
        const s8v* __restrict__ wbst,    // 2 sets: Ws_pi, Wt_pi
        const float* __restrict__ bs, const float* __restrict__ bt,
        const float* __restrict__ be,
        float* __restrict__ xo_f32, ushort_t* __restrict__ xo_b,
        ushort_t* __restrict__ sfb, ushort_t* __restrict__ tfb, int N) {
    int lane = threadIdx.x & 63;
    int wid  = threadIdx.x >> 6;
    int c = lane & 15;
    int g = lane >> 4;

    f4 biasv[4], bsv[4], btv[4];
    #pragma unroll
    for (int nt = 0; nt < 4; nt++) {
        biasv[nt] = *(const f4*)&bias[16 * nt + 4 * g];
        if (DO_ST) {
            bsv[nt] = *(const f4*)&bs[16 * nt + 4 * g] + *(const f4*)&be[16 * nt + 4 * g];
            btv[nt] = *(const f4*)&bt[16 * nt + 4 * g];
        }
    }

    int tiles = (N + 15) >> 4;
    for (int t = blockIdx.x * 4 + wid; t < tiles; t += gridDim.x * 4) {
        int idx = t * 16 + c;
        int ic = idx < N ? idx : N - 1;
        const ushort_t* xr  = xb_in + (size_t)ic * D;
        const ushort_t* sxr = Sx + (size_t)ic * D;
        const ushort_t* ser = Se + (size_t)ic * D;
        s8v xf[2], sxf[2], sef[2];
        #pragma unroll
        for (int kt = 0; kt < 2; kt++) {
            xf[kt]  = *(const s8v*)(xr  + 32 * kt + 8 * g);
            sxf[kt] = *(const s8v*)(sxr + 32 * kt + 8 * g);
            sef[kt] = *(const s8v*)(ser + 32 * kt + 8 * g);
        }
        float inv = inv_deg[ic];

        f4 a0[4], a1[4], a2[4];
        #pragma unroll
        for (int nt = 0; nt < 4; nt++) {
            a0[nt] = (f4){0.f, 0.f, 0.f, 0.f};
            a1[nt] = (f4){0.f, 0.f, 0.f, 0.f};
            a2[nt] = (f4){0.f, 0.f, 0.f, 0.f};
        }
        #pragma unroll
        for (int nt = 0; nt < 4; nt++) {
            #pragma unroll
            for (int kt = 0; kt < 2; kt++) {
                int fo = (nt * 2 + kt) * 64 + lane;
                a0[nt] = __builtin_amdgcn_mfma_f32_16x16x32_bf16(wbn[0 * 512 + fo], xf[kt],  a0[nt], 0, 0, 0);
                a0[nt] = __builtin_amdgcn_mfma_f32_16x16x32_bf16(wbn[1 * 512 + fo], xf[kt],  a0[nt], 0, 0, 0);
                a1[nt] = __builtin_amdgcn_mfma_f32_16x16x32_bf16(wbn[2 * 512 + fo], sxf[kt], a1[nt], 0, 0, 0);
                a1[nt] = __builtin_amdgcn_mfma_f32_16x16x32_bf16(wbn[3 * 512 + fo], sxf[kt], a1[nt], 0, 0, 0);
                a2[nt] = __builtin_amdgcn_mfma_f32_16x16x32_bf16(wbn[4 * 512 + fo], sef[kt], a2[nt], 0, 0, 0);
                a2[nt] = __builtin_amdgcn_mfma_f32_16x16x32_bf16(wbn[5 * 512 + fo], sef[kt], a2[nt], 0, 0, 0);
            }
        }

        f4 v[4];
        #pragma unroll
        for (int nt = 0; nt < 4; nt++) {
            #pragma unroll
            for (int r = 0; r < 4; r++) {
                float vv = a0[nt][r] + inv * (a1[nt][r] + a2[nt][r]) + biasv[nt][r];
                v[nt][r] = LAST ? vv : fmaxf(vv, 0.f);
            }
        }

        if (idx < N) {
            if (LAST) {
                float* orow = xo_f32 + (size_t)idx * D;
                #pragma unroll
                for (int nt = 0; nt < 4; nt++) *(f4*)&orow[16 * nt + 4 * g] = v[nt];
            } else {
                ushort_t* orow = xo_b + (size_t)idx * D;
                #pragma unroll
                for (int nt = 0; nt < 4; nt++) {
                    s4v ov;
                    #pragma unroll
                    for (int r = 0; r < 4; r++) ov[r] = (short)f2bf(v[nt][r]);
                    *(s4v*)(orow + 16 * nt + 4 * g) = ov;
                }
            }
        }

        if (DO_ST) {
            s8v hf[2];
            #pragma unroll
            for (int nt = 0; nt < 4; nt++) {
                #pragma unroll
                for (int r = 0; r < 4; r++) {
                    hf[nt >> 1][((nt & 1) << 2) + r] = (short)f2bf(v[nt][r]);
                }
            }
            f4 so[4], to[4];
            #pragma unroll
            for (int nt = 0; nt < 4; nt++) {
                so[nt] = (f4){0.f, 0.f, 0.f, 0.f};
                to[nt] = (f4){0.f, 0.f, 0.f, 0.f};
            }
            #pragma unroll
            for (int nt = 0; nt < 4; nt++) {
                #pragma unroll
                for (int kt = 0; kt < 2; kt++) {
                    int fo = (nt * 2 + kt) * 64 + lane;
                    so[nt] = __builtin_amdgcn_mfma_f32_16x16x32_bf16(wbst[0 * 512 + fo], hf[kt], so[nt], 0, 0, 0);
                    to[nt] = __builtin_amdgcn_mfma_f32_16x16x32_bf16(wbst[1 * 512 + fo], hf[kt], to[nt], 0, 0, 0);
                }
            }
            if (idx < N) {
                ushort_t* srow = sfb + (size_t)idx * D;
                ushort_t* trow = tfb + (size_t)idx * D;
                #pragma unroll
                for (int nt = 0; nt < 4; nt++) {
                    s4v sv, tv;
                    #pragma unroll
                    for (int r = 0; r < 4; r++) {
                        sv[r] = (short)f2bf(so[nt][r] + bsv[nt][r]);
                        tv[r] = (short)f2bf(to[nt][r] + btv[nt][r]);
                    }
                    *(s4v*)(srow + 16 * nt + 4 * g) = sv;
                    *(s4v*)(trow + 16 * nt + 4 * g) = tv;
                }
            }
        }
    }
}

// ---------------- edge MLP via MFMA: 32-edge-wide waves (double MLP) ----------------
// OCCUPANCY NOTE (measured R4/R9/R10/R12/R18): 2 waves/EU + strided tile map is the
// empirical optimum; occupancy is deliberately capped, leaving VGPR budget free.
// R20 (kept): 32-edge tiles; all 8 sf/tf gathers issue together; +2% measured.
// Depth-2 prefetch of sequential ea/idx streams retained (R15: FETCH-neutral).
// ea_in/out_p may alias in-place; dummy !more re-reads never consumed.
template<int MODE>
__global__ __launch_bounds__(256, 2) void k_edge_mfma(
        const ushort_t* ea_in,
        const int* __restrict__ srcA, const int* __restrict__ dstA,
        const int* __restrict__ emap,
        const ushort_t* __restrict__ sfb, const ushort_t* __restrict__ tfb,
        const s8v* __restrict__ wb,
        const float* __restrict__ b1,
        ushort_t* out_p, float* __restrict__ out_e, int E) {
    int lane = threadIdx.x & 63;
    int wid  = threadIdx.x >> 6;
    int c = lane & 15;
    int g = lane >> 4;

    s8v weh[4][2], wel[4][2], w1f[4][2];
    #pragma unroll
    for (int nt = 0; nt < 4; nt++) {
        #pragma unroll
        for (int kt = 0; kt < 2; kt++) {
            int f = nt * 2 + kt;
            weh[nt][kt] = wb[0 * 512 + f * 64 + lane];
            wel[nt][kt] = wb[1 * 512 + f * 64 + lane];
            w1f[nt][kt] = wb[2 * 512 + f * 64 + lane];
        }
    }
    f4 b1v[4];
    #pragma unroll
    for (int nt = 0; nt < 4; nt++) {
        b1v[nt] = *(const f4*)&b1[16 * nt + 4 * g];
    }

    int tiles = (E + 31) >> 5;     // 32 edges per tile
    int S = gridDim.x * 4;
    int t = blockIdx.x * 4 + wid;
    if (t >= tiles) return;

    int idxA = t * 32 + c;
    int idxB = idxA + 16;
    int icA = idxA < E ? idxA : E - 1;
    int icB = idxB < E ? idxB : E - 1;
    const ushort_t* earA = ea_in + (size_t)icA * D;
    const ushort_t* earB = ea_in + (size_t)icB * D;
    s8v eaA0 = *(const s8v*)(earA + 8 * g);
    s8v eaA1 = *(const s8v*)(earA + 32 + 8 * g);
    s8v eaB0 = *(const s8v*)(earB + 8 * g);
    s8v eaB1 = *(const s8v*)(earB + 32 + 8 * g);
    int sA = srcA[icA], dA = dstA[icA];
    int sB = srcA[icB], dB = dstA[icB];
    int emA = (MODE == 1) ? emap[icA] : 0;
    int emB = (MODE == 1) ? emap[icB] : 0;

    while (true) {
        int tn = t + S;
        bool more = (tn < tiles);
        int idxAn = more ? tn * 32 + c : idxA;
        int idxBn = more ? tn * 32 + 16 + c : idxB;
        int icAn = idxAn < E ? idxAn : E - 1;
        int icBn = idxBn < E ? idxBn : E - 1;
        const ushort_t* earAn = ea_in + (size_t)icAn * D;
        const ushort_t* earBn = ea_in + (size_t)icBn * D;
        s8v eaA0n = *(const s8v*)(earAn + 8 * g);
        s8v eaA1n = *(const s8v*)(earAn + 32 + 8 * g);
        s8v eaB0n = *(const s8v*)(earBn + 8 * g);
        s8v eaB1n = *(const s8v*)(earBn + 32 + 8 * g);
        int sAn = srcA[icAn], dAn = dstA[icAn];
        int sBn = srcA[icBn], dBn = dstA[icBn];
        int emAn = (MODE == 1) ? emap[icAn] : 0;
        int emBn = (MODE == 1) ? emap[icBn] : 0;

        const ushort_t* srA = sfb + (size_t)sA * D;
        const ushort_t* trA = tfb + (size_t)dA * D;
        const ushort_t* srB = sfb + (size_t)sB * D;
        const ushort_t* trB = tfb + (size_t)dB * D;
        s4v sgA[4], tgA[4], sgB[4], tgB[4];
        #pragma unroll
        for (int nt = 0; nt < 4; nt++) {
            sgA[nt] = *(const s4v*)(srA + 16 * nt + 4 * g);
            tgA[nt] = *(const s4v*)(trA + 16 * nt + 4 * g);
            sgB[nt] = *(const s4v*)(srB + 16 * nt + 4 * g);
            tgB[nt] = *(const s4v*)(trB + 16 * nt + 4 * g);
        }

        // ================= sub-tile A =================
        {
            f4 acc[4];
            #pragma unroll
            for (int nt = 0; nt < 4; nt++) acc[nt] = (f4){0.f, 0.f, 0.f, 0.f};
            #pragma unroll
            for (int nt = 0; nt < 4; nt++) {
                #pragma unroll
                for (int kt = 0; kt < 2; kt++) {
                    s8v av = (kt == 0) ? eaA0 : eaA1;
                    acc[nt] = __builtin_amdgcn_mfma_f32_16x16x32_bf16(weh[nt][kt], av, acc[nt], 0, 0, 0);
                    acc[nt] = __builtin_amdgcn_mfma_f32_16x16x32_bf16(wel[nt][kt], av, acc[nt], 0, 0, 0);
                }
            }
            s8v hf[2];
            #pragma unroll
            for (int nt = 0; nt < 4; nt++) {
                #pragma unroll
                for (int r = 0; r < 4; r++) {
                    float hv = acc[nt][r] + bf2f((ushort_t)sgA[nt][r]) + bf2f((ushort_t)tgA[nt][r]);
                    hv = fmaxf(hv, 0.f);
                    hf[nt >> 1][((nt & 1) << 2) + r] = (short)f2bf(hv);
                }
            }
            f4 out[4];
            #pragma unroll
            for (int nt = 0; nt < 4; nt++) out[nt] = (f4){0.f, 0.f, 0.f, 0.f};
            #pragma unroll
            for (int nt = 0; nt < 4; nt++) {
                #pragma unroll
                for (int kt = 0; kt < 2; kt++) {
                    out[nt] = __builtin_amdgcn_mfma_f32_16x16x32_bf16(w1f[nt][kt], hf[kt], out[nt], 0, 0, 0);
                }
            }
            if (idxA < E) {
                #pragma unroll
                for (int nt = 0; nt < 4; nt++) out[nt] += b1v[nt];
                ushort_t* prow = out_p + (size_t)idxA * D;
                #pragma unroll
                for (int nt = 0; nt < 4; nt++) {
                    s4v ov;
                    #pragma unroll
                    for (int r = 0; r < 4; r++) ov[r] = (short)f2bf(out[nt][r]);
                    *(s4v*)(prow + 16 * nt + 4 * g) = ov;
                }
                if (MODE == 1) {
                    float* orow = out_e + (size_t)emA * D;
                    #pragma unroll
                    for (int nt = 0; nt < 4; nt++) *(f4*)&orow[16 * nt + 4 * g] = out[nt];
                }
            }
        }

        // ================= sub-tile B =================
        {
            f4 acc[4];
            #pragma unroll
            for (int nt = 0; nt < 4; nt++) acc[nt] = (f4){0.f, 0.f, 0.f, 0.f};
            #pragma unroll
            for (int nt = 0; nt < 4; nt++) {
                #pragma unroll
                for (int kt = 0; kt < 2; kt++) {
                    s8v av = (kt == 0) ? eaB0 : eaB1;
                    acc[nt] = __builtin_amdgcn_mfma_f32_16x16x32_bf16(weh[nt][kt], av, acc[nt], 0, 0, 0);
                    acc[nt] = __builtin_amdgcn_mfma_f32_16x16x32_bf16(wel[nt][kt], av, acc[nt], 0, 0, 0);
                }
            }
            s8v hf[2];
            #pragma unroll
            for (int nt = 0; nt < 4; nt++) {
                #pragma unroll
                for (int r = 0; r < 4; r++) {
                    float hv = acc[nt][r] + bf2f((ushort_t)sgB[nt][r]) + bf2f((ushort_t)tgB[nt][r]);
                    hv = fmaxf(hv, 0.f);
                    hf[nt >> 1][((nt & 1) << 2) + r] = (short)f2bf(hv);
                }
            }
            f4 out[4];
            #pragma unroll
            for (int nt = 0; nt < 4; nt++) out[nt] = (f4){0.f, 0.f, 0.f, 0.f};
            #pragma unroll
            for (int nt = 0; nt < 4; nt++) {
                #pragma unroll
                for (int kt = 0; kt < 2; kt++) {
                    out[nt] = __builtin_amdgcn_mfma_f32_16x16x32_bf16(w1f[nt][kt], hf[kt], out[nt], 0, 0, 0);
                }
            }
            if (idxB < E) {
                #pragma unroll
                for (int nt = 0; nt < 4; nt++) out[nt] += b1v[nt];
                ushort_t* prow = out_p + (size_t)idxB * D;
                #pragma unroll
                for (int nt = 0; nt < 4; nt++) {
                    s4v ov;
                    #pragma unroll
                    for (int r = 0; r < 4; r++) ov[r] = (short)f2bf(out[nt][r]);
                    *(s4v*)(prow + 16 * nt + 4 * g) = ov;
                }
                if (MODE == 1) {
                    float* orow = out_e + (size_t)emB * D;
                    #pragma unroll
                    for (int nt = 0; nt < 4; nt++) *(f4*)&orow[16 * nt + 4 * g] = out[nt];
                }
            }
        }

        if (!more) break;
        t = tn; idxA = idxAn; idxB = idxBn;
        eaA0 = eaA0n; eaA1 = eaA1n; eaB0 = eaB0n; eaB1 = eaB1n;
        sA = sAn; dA = dAn; sB = sBn; dB = dBn; emA = emAn; emB = emBn;
    }
}

extern "C" void kernel_launch(void* const* d_in, const int* in_sizes, int n_in,
                              void* d_out, int out_size, void* d_ws, size_t ws_size,
                              hipStream_t stream) {
    const float* x0  = (const float*)d_in[0];
    const int*   ei  = (const int*)d_in[1];
    const float* ea0 = (const float*)d_in[2];
    const float* Wr  = (const float*)d_in[3];
    const float* Wn  = (const float*)d_in[4];
    const float* We  = (const float*)d_in[5];
    const float* b   = (const float*)d_in[6];
    const float* EWe = (const float*)d_in[7];
    const float* Ebe = (const float*)d_in[8];
    const float* EWs = (const float*)d_in[9];
    const float* Ebs = (const float*)d_in[10];
    const float* EWt = (const float*)d_in[11];
    const float* Ebt = (const float*)d_in[12];
    const float* EW1 = (const float*)d_in[13];
    const float* Eb1 = (const float*)d_in[14];

    const int N = in_sizes[0] / D;
    const int E = in_sizes[1] / 2;
    const int* src = ei;
    const int* dst = ei + E;

    char* ws = (char*)d_ws;
    size_t off = 0;
    auto alloc = [&](size_t bytes) {
        void* p = ws + off;
        off += (bytes + 255) & ~(size_t)255;
        return p;
    };
    int*      cntcur    = (int*)alloc((size_t)2 * N * 4);
    int*      cnt       = cntcur;
    int*      cursor    = cntcur + N;
    int*      row_start = (int*)alloc((size_t)(N + 1) * 4);
    int*      eids      = (int*)alloc((size_t)E * 4);
    int*      srcs      = (int*)alloc((size_t)E * 4);
    int*      pdst      = (int*)alloc((size_t)E * 4);
    int*      pos       = (int*)alloc((size_t)E * 4);
    float*    inv_deg   = (float*)alloc((size_t)N * 4);
    ushort_t* Sx        = (ushort_t*)alloc((size_t)N * D * 2);
    ushort_t* Se        = (ushort_t*)alloc((size_t)N * D * 2);
    ushort_t* xb0       = (ushort_t*)alloc((size_t)N * D * 2);
    ushort_t* xb1       = (ushort_t*)alloc((size_t)N * D * 2);
    ushort_t* sfb       = (ushort_t*)alloc((size_t)N * D * 2);
    ushort_t* tfb       = (ushort_t*)alloc((size_t)N * D * 2);
    s8v*      wbuf      = (s8v*)alloc((size_t)28 * 512 * 16);
    ushort_t* pea       = (ushort_t*)alloc((size_t)E * D * 2);

    float* outx  = (float*)d_out;
    float* outea = (float*)d_out + (size_t)N * D;

    hipMemsetAsync(cntcur, 0, (size_t)2 * N * 4, stream);
    k_count<<<(E + 255) / 256, 256, 0, stream>>>(dst, cnt, E);
    k_scan<<<1, 1024, 0, stream>>>(cnt, row_start, inv_deg, N);
    k_fill<<<(E + 255) / 256, 256, 0, stream>>>(src, dst, row_start, cursor,
                                                eids, srcs, pdst, pos, E);
    {
        int pblocks = (E * 8 + 255) / 256;
        int xblocks = (N * D / 8 + 255) / 256;
        k_permcvt<<<pblocks + xblocks, 256, 0, stream>>>(ea0, pos, pea, E, x0, xb0, N * D / 8, pblocks);
    }
    k_prepw<<<28, 64, 0, stream>>>(Wr, Wn, We, EWe, EW1, EWs, EWt, wbuf);

    dim3 b644(64, 4);
    const s8v* wbn0  = wbuf;               // conv layer 0: 6 sets
    const s8v* wbn1  = wbuf + 6 * 512;
    const s8v* wbn2  = wbuf + 12 * 512;
    const s8v* wbe0  = wbuf + 18 * 512;    // edge layer 0: 3 sets
    const s8v* wbe1  = wbuf + 21 * 512;
    const s8v* wbst0 = wbuf + 24 * 512;    // st layer 0: 2 sets
    const s8v* wbst1 = wbuf + 26 * 512;

    // ---- layer 0 ----
    k_agg_seq<<<(N + 3) / 4, b644, 0, stream>>>(xb0, pea, row_start, srcs, Sx, Se, N, 0);
    k_node_mfma<1, 0><<<1024, 256, 0, stream>>>(xb0, Sx, Se, inv_deg, wbn0, b,
                                                wbst0, Ebs, Ebt, Ebe,
                                                nullptr, xb1, sfb, tfb, N);
    k_edge_mfma<0><<<2048, 256, 0, stream>>>(pea, srcs, pdst, eids, sfb, tfb,
                                             wbe0, Eb1, pea, nullptr, E);

    // ---- layer 1 ----
    k_agg_seq<<<(N + 3) / 4, b644, 0, stream>>>(xb1, pea, row_start, srcs, Sx, Se, N, 0);
    k_node_mfma<1, 0><<<1024, 256, 0, stream>>>(xb1, Sx, Se, inv_deg, wbn1, b + D,
                                                wbst1, Ebs + D, Ebt + D, Ebe + D,
                                                nullptr, xb0, sfb, tfb, N);
    k_edge_mfma<1><<<2048, 256, 0, stream>>>(pea, srcs, pdst, eids, sfb, tfb,
                                             wbe1, Eb1 + D, pea, outea, E);

    // ---- layer 2 ----
    k_agg_seq<<<(N + 3) / 4, b644, 0, stream>>>(xb0, pea, row_start, srcs, Sx, Se, N, 0);
    k_node_mfma<0, 1><<<1024, 256, 0, stream>>>(xb0, Sx, Se, inv_deg, wbn2, b + 2 * D,
                                                nullptr, nullptr, nullptr, nullptr,
                                                outx, nullptr, nullptr, nullptr, N);
}

// Round 22
// 645.174 us; speedup vs baseline: 1.0683x; 1.0683x over previous
//
#include <hip/hip_runtime.h>

#define D 64
#define LAYERS 3

typedef float  f4  __attribute__((ext_vector_type(4)));
typedef short  s8v __attribute__((ext_vector_type(8)));
typedef short  s4v __attribute__((ext_vector_type(4)));
typedef unsigned short ushort_t;

__device__ __forceinline__ unsigned short f2bf(float x) {
    unsigned int u = __float_as_uint(x);
    unsigned int r = (u + 0x7fffu + ((u >> 16) & 1u)) >> 16;
    return (unsigned short)r;
}
__device__ __forceinline__ float bf2f(unsigned short h) {
    return __uint_as_float(((unsigned int)h) << 16);
}

// ---------------- CSR build ----------------

__global__ void k_count(const int* __restrict__ dst, int* __restrict__ cnt, int E) {
    int e = blockIdx.x * blockDim.x + threadIdx.x;
    if (e < E) atomicAdd(&cnt[dst[e]], 1);
}

__global__ __launch_bounds__(1024) void k_scan(const int* __restrict__ cnt,
                                               int* __restrict__ row_start,
                                               float* __restrict__ inv_deg, int N) {
    __shared__ int buf[1024];
    int tid = threadIdx.x;
    int per = (N + 1023) >> 10;
    int begin = tid * per;
    int end = min(begin + per, N);
    int s = 0;
    for (int i = begin; i < end; i++) s += cnt[i];
    buf[tid] = s;
    __syncthreads();
    for (int off = 1; off < 1024; off <<= 1) {
        int v = 0;
        if (tid >= off) v = buf[tid - off];
        __syncthreads();
        buf[tid] += v;
        __syncthreads();
    }
    int run = buf[tid] - s;
    for (int i = begin; i < end; i++) {
        row_start[i] = run;
        int c = cnt[i];
        inv_deg[i] = 1.0f / (float)(c > 1 ? c : 1);
        run += c;
    }
    if (begin < N && end == N) row_start[N] = run;
}

// light fill: indices only (row-copy fusion measured -76us WORSE in R16).
__global__ void k_fill(const int* __restrict__ src, const int* __restrict__ dst,
                       const int* __restrict__ row_start, int* __restrict__ cursor,
                       int* __restrict__ eids, int* __restrict__ srcs,
                       int* __restrict__ pdst, int* __restrict__ pos, int E) {
    int e = blockIdx.x * blockDim.x + threadIdx.x;
    if (e >= E) return;
    int d = dst[e];
    int p = row_start[d] + atomicAdd(&cursor[d], 1);
    eids[p] = e;
    srcs[p] = src[e];
    pdst[p] = d;
    pos[e] = p;
}

// ---------------- fused: permute ea0 -> pea (bf16, p-order) AND x0 -> xb (bf16) ----------------
__global__ __launch_bounds__(256) void k_permcvt(const float* __restrict__ ea,
                                                 const int* __restrict__ pos,
                                                 ushort_t* __restrict__ pea, int E,
                                                 const float* __restrict__ x,
                                                 ushort_t* __restrict__ xb, int xtotal8,
                                                 int pblocks) {
    if ((int)blockIdx.x < pblocks) {
        int t = blockIdx.x * blockDim.x + threadIdx.x;
        int e = t >> 3;
        if (e >= E) return;
        int seg = t & 7;
        const float* rp = ea + (size_t)e * D + seg * 8;
        f4 a0 = *(const f4*)rp;
        f4 a1 = *(const f4*)(rp + 4);
        s8v o;
        #pragma unroll
        for (int i = 0; i < 4; i++) {
            o[i]     = (short)f2bf(a0[i]);
            o[4 + i] = (short)f2bf(a1[i]);
        }
        int p = pos[e];
        *(s8v*)(pea + (size_t)p * D + seg * 8) = o;
    } else {
        int t = (blockIdx.x - pblocks) * blockDim.x + threadIdx.x;
        if (t >= xtotal8) return;
        const float* rp = x + (size_t)t * 8;
        f4 a0 = *(const f4*)rp;
        f4 a1 = *(const f4*)(rp + 4);
        s8v o;
        #pragma unroll
        for (int i = 0; i < 4; i++) {
            o[i]     = (short)f2bf(a0[i]);
            o[4 + i] = (short)f2bf(a1[i]);
        }
        *(s8v*)(xb + (size_t)t * 8) = o;
    }
}

// ---------------- prepack ALL weight fragments (per-lane layout) ----------------
__global__ __launch_bounds__(64) void k_prepw(const float* __restrict__ Wr,
                                              const float* __restrict__ Wn,
                                              const float* __restrict__ Wec,
                                              const float* __restrict__ EWe,
                                              const float* __restrict__ EW1,
                                              const float* __restrict__ EWs,
                                              const float* __restrict__ EWt,
                                              s8v* __restrict__ wbuf) {
    int set = blockIdx.x;
    const float* Wsrc;
    int order, part;   // order: 0=natural,1=pi ; part: 0=hi,1=lo,2=single
    if (set < 18) {
        int i = set / 6, r = set % 6, m = r >> 1;
        part = r & 1;
        order = 0;
        const float* base = (m == 0) ? Wr : (m == 1) ? Wn : Wec;
        Wsrc = base + (size_t)i * D * D;
    } else if (set < 24) {
        int j = (set - 18) / 3, r = (set - 18) % 3;
        if (r == 2) { Wsrc = EW1 + (size_t)j * D * D; part = 2; order = 1; }
        else        { Wsrc = EWe + (size_t)j * D * D; part = r; order = 0; }
    } else {
        int j = (set - 24) / 2, r = (set - 24) % 2;
        Wsrc = ((r == 0) ? EWs : EWt) + (size_t)j * D * D;
        part = 2; order = 1;
    }
    int lane = threadIdx.x;
    int c = lane & 15, g = lane >> 4;
    s8v* wb = wbuf + (size_t)set * 512;
    #pragma unroll
    for (int nt = 0; nt < 4; nt++) {
        #pragma unroll
        for (int kt = 0; kt < 2; kt++) {
            s8v frag;
            #pragma unroll
            for (int i = 0; i < 8; i++) {
                int k = (order == 0) ? (32 * kt + 8 * g + i)
                                     : (32 * kt + 16 * (i >> 2) + 4 * g + (i & 3));
                float w = Wsrc[k * D + 16 * nt + c];
                unsigned short hb = f2bf(w);
                frag[i] = (part == 1) ? (short)f2bf(w - bf2f(hb)) : (short)hb;
            }
            wb[(nt * 2 + kt) * 64 + lane] = frag;
        }
    }
}

// ---------------- aggregation, vectorized (G13): 16B loads, 8 rows in flight ----------------
// NOTE (R18): ILP-2/16-row restructuring measured WORSE — keep simple 8-row loop.
// NOTE (R21): LDS occupancy throttle (4 blocks/CU) measured WORSE (+44us) — the xb
// gather (6.4MB) fits L2 even at full occupancy; agg needs waves for latency hiding.
__global__ __launch_bounds__(256) void k_agg_seq(const ushort_t* __restrict__ xb,
                                                 const ushort_t* __restrict__ pea,
                                                 const int* __restrict__ row_start,
                                                 const int* __restrict__ srcs,
                                                 ushort_t* __restrict__ Sx, ushort_t* __restrict__ Se,
                                                 int N) {
    int n = blockIdx.x * 4 + threadIdx.y;
    if (n >= N) return;
    int lane = threadIdx.x;
    int r = lane >> 3;       // row slot 0..7
    int o = lane & 7;        // feature octet
    int p0 = row_start[n], p1 = row_start[n + 1];
    f4 ax0 = (f4){0.f, 0.f, 0.f, 0.f}, ax1 = (f4){0.f, 0.f, 0.f, 0.f};
    f4 ae0 = (f4){0.f, 0.f, 0.f, 0.f}, ae1 = (f4){0.f, 0.f, 0.f, 0.f};
    for (int p = p0 + r; p < p1; p += 8) {
        s8v ev = *(const s8v*)(pea + (size_t)p * D + o * 8);
        int sidx = srcs[p];
        s8v xv = *(const s8v*)(xb + (size_t)sidx * D + o * 8);
        #pragma unroll
        for (int i = 0; i < 4; i++) {
            ae0[i] += bf2f((ushort_t)ev[i]);
            ae1[i] += bf2f((ushort_t)ev[4 + i]);
            ax0[i] += bf2f((ushort_t)xv[i]);
            ax1[i] += bf2f((ushort_t)xv[4 + i]);
        }
    }
    #pragma unroll
    for (int off = 8; off < 64; off <<= 1) {
        #pragma unroll
        for (int i = 0; i < 4; i++) {
            ax0[i] += __shfl_xor(ax0[i], off);
            ax1[i] += __shfl_xor(ax1[i], off);
            ae0[i] += __shfl_xor(ae0[i], off);
            ae1[i] += __shfl_xor(ae1[i], off);
        }
    }
    if (r == 0) {
        s8v sx, se;
        #pragma unroll
        for (int i = 0; i < 4; i++) {
            sx[i]     = (short)f2bf(ax0[i]);
            sx[4 + i] = (short)f2bf(ax1[i]);
            se[i]     = (short)f2bf(ae0[i]);
            se[4 + i] = (short)f2bf(ae1[i]);
        }
        *(s8v*)(Sx + (size_t)n * D + o * 8) = sx;
        *(s8v*)(Se + (size_t)n * D + o * 8) = se;
    }
}

// ---------------- fused node update + s/t features via MFMA (zero LDS) ----------------
template<int DO_ST, int LAST>
__global__ __launch_bounds__(256) void k_node_mfma(
        const ushort_t* __restrict__ xb_in,
        const ushort_t* __restrict__ Sx, const ushort_t* __restrict__ Se,
        const float* __restrict__ inv_deg,
        const s8v* __restrict__ wbn,     // 6 sets: Wr_hi,Wr_lo,Wn_hi,Wn_lo,We_hi,We_lo
        const float* __restrict__ bias,
        const s8v* __restrict__ wbst,    // 2 sets: Ws_pi, Wt_pi
        const float* __restrict__ bs, const float* __restrict__ bt,
        const float* __restrict__ be,
        float* __restrict__ xo_f32, ushort_t* __restrict__ xo_b,
        ushort_t* __restrict__ sfb, ushort_t* __restrict__ tfb, int N) {
    int lane = threadIdx.x & 63;
    int wid  = threadIdx.x >> 6;
    int c = lane & 15;
    int g = lane >> 4;

    f4 biasv[4], bsv[4], btv[4];
    #pragma unroll
    for (int nt = 0; nt < 4; nt++) {
        biasv[nt] = *(const f4*)&bias[16 * nt + 4 * g];
        if (DO_ST) {
            bsv[nt] = *(const f4*)&bs[16 * nt + 4 * g] + *(const f4*)&be[16 * nt + 4 * g];
            btv[nt] = *(const f4*)&bt[16 * nt + 4 * g];
        }
    }

    int tiles = (N + 15) >> 4;
    for (int t = blockIdx.x * 4 + wid; t < tiles; t += gridDim.x * 4) {
        int idx = t * 16 + c;
        int ic = idx < N ? idx : N - 1;
        const ushort_t* xr  = xb_in + (size_t)ic * D;
        const ushort_t* sxr = Sx + (size_t)ic * D;
        const ushort_t* ser = Se + (size_t)ic * D;
        s8v xf[2], sxf[2], sef[2];
        #pragma unroll
        for (int kt = 0; kt < 2; kt++) {
            xf[kt]  = *(const s8v*)(xr  + 32 * kt + 8 * g);
            sxf[kt] = *(const s8v*)(sxr + 32 * kt + 8 * g);
            sef[kt] = *(const s8v*)(ser + 32 * kt + 8 * g);
        }
        float inv = inv_deg[ic];

        f4 a0[4], a1[4], a2[4];
        #pragma unroll
        for (int nt = 0; nt < 4; nt++) {
            a0[nt] = (f4){0.f, 0.f, 0.f, 0.f};
            a1[nt] = (f4){0.f, 0.f, 0.f, 0.f};
            a2[nt] = (f4){0.f, 0.f, 0.f, 0.f};
        }
        #pragma unroll
        for (int nt = 0; nt < 4; nt++) {
            #pragma unroll
            for (int kt = 0; kt < 2; kt++) {
                int fo = (nt * 2 + kt) * 64 + lane;
                a0[nt] = __builtin_amdgcn_mfma_f32_16x16x32_bf16(wbn[0 * 512 + fo], xf[kt],  a0[nt], 0, 0, 0);
                a0[nt] = __builtin_amdgcn_mfma_f32_16x16x32_bf16(wbn[1 * 512 + fo], xf[kt],  a0[nt], 0, 0, 0);
                a1[nt] = __builtin_amdgcn_mfma_f32_16x16x32_bf16(wbn[2 * 512 + fo], sxf[kt], a1[nt], 0, 0, 0);
                a1[nt] = __builtin_amdgcn_mfma_f32_16x16x32_bf16(wbn[3 * 512 + fo], sxf[kt], a1[nt], 0, 0, 0);
                a2[nt] = __builtin_amdgcn_mfma_f32_16x16x32_bf16(wbn[4 * 512 + fo], sef[kt], a2[nt], 0, 0, 0);
                a2[nt] = __builtin_amdgcn_mfma_f32_16x16x32_bf16(wbn[5 * 512 + fo], sef[kt], a2[nt], 0, 0, 0);
            }
        }

        f4 v[4];
        #pragma unroll
        for (int nt = 0; nt < 4; nt++) {
            #pragma unroll
            for (int r = 0; r < 4; r++) {
                float vv = a0[nt][r] + inv * (a1[nt][r] + a2[nt][r]) + biasv[nt][r];
                v[nt][r] = LAST ? vv : fmaxf(vv, 0.f);
            }
        }

        if (idx < N) {
            if (LAST) {
                float* orow = xo_f32 + (size_t)idx * D;
                #pragma unroll
                for (int nt = 0; nt < 4; nt++) *(f4*)&orow[16 * nt + 4 * g] = v[nt];
            } else {
                ushort_t* orow = xo_b + (size_t)idx * D;
                #pragma unroll
                for (int nt = 0; nt < 4; nt++) {
                    s4v ov;
                    #pragma unroll
                    for (int r = 0; r < 4; r++) ov[r] = (short)f2bf(v[nt][r]);
                    *(s4v*)(orow + 16 * nt + 4 * g) = ov;
                }
            }
        }

        if (DO_ST) {
            s8v hf[2];
            #pragma unroll
            for (int nt = 0; nt < 4; nt++) {
                #pragma unroll
                for (int r = 0; r < 4; r++) {
                    hf[nt >> 1][((nt & 1) << 2) + r] = (short)f2bf(v[nt][r]);
                }
            }
            f4 so[4], to[4];
            #pragma unroll
            for (int nt = 0; nt < 4; nt++) {
                so[nt] = (f4){0.f, 0.f, 0.f, 0.f};
                to[nt] = (f4){0.f, 0.f, 0.f, 0.f};
            }
            #pragma unroll
            for (int nt = 0; nt < 4; nt++) {
                #pragma unroll
                for (int kt = 0; kt < 2; kt++) {
                    int fo = (nt * 2 + kt) * 64 + lane;
                    so[nt] = __builtin_amdgcn_mfma_f32_16x16x32_bf16(wbst[0 * 512 + fo], hf[kt], so[nt], 0, 0, 0);
                    to[nt] = __builtin_amdgcn_mfma_f32_16x16x32_bf16(wbst[1 * 512 + fo], hf[kt], to[nt], 0, 0, 0);
                }
            }
            if (idx < N) {
                ushort_t* srow = sfb + (size_t)idx * D;
                ushort_t* trow = tfb + (size_t)idx * D;
                #pragma unroll
                for (int nt = 0; nt < 4; nt++) {
                    s4v sv, tv;
                    #pragma unroll
                    for (int r = 0; r < 4; r++) {
                        sv[r] = (short)f2bf(so[nt][r] + bsv[nt][r]);
                        tv[r] = (short)f2bf(to[nt][r] + btv[nt][r]);
                    }
                    *(s4v*)(srow + 16 * nt + 4 * g) = sv;
                    *(s4v*)(trow + 16 * nt + 4 * g) = tv;
                }
            }
        }
    }
}

// ---------------- edge MLP via MFMA: 32-edge-wide waves (double MLP) ----------------
// OCCUPANCY NOTE (measured R4/R9/R10/R12/R18): 2 waves/EU + strided tile map is the
// empirical optimum; occupancy is deliberately capped, leaving VGPR budget free.
// R20 (kept): 32-edge tiles; all 8 sf/tf gathers issue together; +2% measured.
// Depth-2 prefetch of sequential ea/idx streams retained (R15: FETCH-neutral).
// ea_in/out_p may alias in-place; dummy !more re-reads never consumed.
template<int MODE>
__global__ __launch_bounds__(256, 2) void k_edge_mfma(
        const ushort_t* ea_in,
        const int* __restrict__ srcA, const int* __restrict__ dstA,
        const int* __restrict__ emap,
        const ushort_t* __restrict__ sfb, const ushort_t* __restrict__ tfb,
        const s8v* __restrict__ wb,
        const float* __restrict__ b1,
        ushort_t* out_p, float* __restrict__ out_e, int E) {
    int lane = threadIdx.x & 63;
    int wid  = threadIdx.x >> 6;
    int c = lane & 15;
    int g = lane >> 4;

    s8v weh[4][2], wel[4][2], w1f[4][2];
    #pragma unroll
    for (int nt = 0; nt < 4; nt++) {
        #pragma unroll
        for (int kt = 0; kt < 2; kt++) {
            int f = nt * 2 + kt;
            weh[nt][kt] = wb[0 * 512 + f * 64 + lane];
            wel[nt][kt] = wb[1 * 512 + f * 64 + lane];
            w1f[nt][kt] = wb[2 * 512 + f * 64 + lane];
        }
    }
    f4 b1v[4];
    #pragma unroll
    for (int nt = 0; nt < 4; nt++) {
        b1v[nt] = *(const f4*)&b1[16 * nt + 4 * g];
    }

    int tiles = (E + 31) >> 5;     // 32 edges per tile
    int S = gridDim.x * 4;
    int t = blockIdx.x * 4 + wid;
    if (t >= tiles) return;

    int idxA = t * 32 + c;
    int idxB = idxA + 16;
    int icA = idxA < E ? idxA : E - 1;
    int icB = idxB < E ? idxB : E - 1;
    const ushort_t* earA = ea_in + (size_t)icA * D;
    const ushort_t* earB = ea_in + (size_t)icB * D;
    s8v eaA0 = *(const s8v*)(earA + 8 * g);
    s8v eaA1 = *(const s8v*)(earA + 32 + 8 * g);
    s8v eaB0 = *(const s8v*)(earB + 8 * g);
    s8v eaB1 = *(const s8v*)(earB + 32 + 8 * g);
    int sA = srcA[icA], dA = dstA[icA];
    int sB = srcA[icB], dB = dstA[icB];
    int emA = (MODE == 1) ? emap[icA] : 0;
    int emB = (MODE == 1) ? emap[icB] : 0;

    while (true) {
        int tn = t + S;
        bool more = (tn < tiles);
        int idxAn = more ? tn * 32 + c : idxA;
        int idxBn = more ? tn * 32 + 16 + c : idxB;
        int icAn = idxAn < E ? idxAn : E - 1;
        int icBn = idxBn < E ? idxBn : E - 1;
        const ushort_t* earAn = ea_in + (size_t)icAn * D;
        const ushort_t* earBn = ea_in + (size_t)icBn * D;
        s8v eaA0n = *(const s8v*)(earAn + 8 * g);
        s8v eaA1n = *(const s8v*)(earAn + 32 + 8 * g);
        s8v eaB0n = *(const s8v*)(earBn + 8 * g);
        s8v eaB1n = *(const s8v*)(earBn + 32 + 8 * g);
        int sAn = srcA[icAn], dAn = dstA[icAn];
        int sBn = srcA[icBn], dBn = dstA[icBn];
        int emAn = (MODE == 1) ? emap[icAn] : 0;
        int emBn = (MODE == 1) ? emap[icBn] : 0;

        const ushort_t* srA = sfb + (size_t)sA * D;
        const ushort_t* trA = tfb + (size_t)dA * D;
        const ushort_t* srB = sfb + (size_t)sB * D;
        const ushort_t* trB = tfb + (size_t)dB * D;
        s4v sgA[4], tgA[4], sgB[4], tgB[4];
        #pragma unroll
        for (int nt = 0; nt < 4; nt++) {
            sgA[nt] = *(const s4v*)(srA + 16 * nt + 4 * g);
            tgA[nt] = *(const s4v*)(trA + 16 * nt + 4 * g);
            sgB[nt] = *(const s4v*)(srB + 16 * nt + 4 * g);
            tgB[nt] = *(const s4v*)(trB + 16 * nt + 4 * g);
        }

        // ================= sub-tile A =================
        {
            f4 acc[4];
            #pragma unroll
            for (int nt = 0; nt < 4; nt++) acc[nt] = (f4){0.f, 0.f, 0.f, 0.f};
            #pragma unroll
            for (int nt = 0; nt < 4; nt++) {
                #pragma unroll
                for (int kt = 0; kt < 2; kt++) {
                    s8v av = (kt == 0) ? eaA0 : eaA1;
                    acc[nt] = __builtin_amdgcn_mfma_f32_16x16x32_bf16(weh[nt][kt], av, acc[nt], 0, 0, 0);
                    acc[nt] = __builtin_amdgcn_mfma_f32_16x16x32_bf16(wel[nt][kt], av, acc[nt], 0, 0, 0);
                }
            }
            s8v hf[2];
            #pragma unroll
            for (int nt = 0; nt < 4; nt++) {
                #pragma unroll
                for (int r = 0; r < 4; r++) {
                    float hv = acc[nt][r] + bf2f((ushort_t)sgA[nt][r]) + bf2f((ushort_t)tgA[nt][r]);
                    hv = fmaxf(hv, 0.f);
                    hf[nt >> 1][((nt & 1) << 2) + r] = (short)f2bf(hv);
                }
            }
            f4 out[4];
            #pragma unroll
            for (int nt = 0; nt < 4; nt++) out[nt] = (f4){0.f, 0.f, 0.f, 0.f};
            #pragma unroll
            for (int nt = 0; nt < 4; nt++) {
                #pragma unroll
                for (int kt = 0; kt < 2; kt++) {
                    out[nt] = __builtin_amdgcn_mfma_f32_16x16x32_bf16(w1f[nt][kt], hf[kt], out[nt], 0, 0, 0);
                }
            }
            if (idxA < E) {
                #pragma unroll
                for (int nt = 0; nt < 4; nt++) out[nt] += b1v[nt];
                ushort_t* prow = out_p + (size_t)idxA * D;
                #pragma unroll
                for (int nt = 0; nt < 4; nt++) {
                    s4v ov;
                    #pragma unroll
                    for (int r = 0; r < 4; r++) ov[r] = (short)f2bf(out[nt][r]);
                    *(s4v*)(prow + 16 * nt + 4 * g) = ov;
                }
                if (MODE == 1) {
                    float* orow = out_e + (size_t)emA * D;
                    #pragma unroll
                    for (int nt = 0; nt < 4; nt++) *(f4*)&orow[16 * nt + 4 * g] = out[nt];
                }
            }
        }

        // ================= sub-tile B =================
        {
            f4 acc[4];
            #pragma unroll
            for (int nt = 0; nt < 4; nt++) acc[nt] = (f4){0.f, 0.f, 0.f, 0.f};
            #pragma unroll
            for (int nt = 0; nt < 4; nt++) {
                #pragma unroll
                for (int kt = 0; kt < 2; kt++) {
                    s8v av = (kt == 0) ? eaB0 : eaB1;
                    acc[nt] = __builtin_amdgcn_mfma_f32_16x16x32_bf16(weh[nt][kt], av, acc[nt], 0, 0, 0);
                    acc[nt] = __builtin_amdgcn_mfma_f32_16x16x32_bf16(wel[nt][kt], av, acc[nt], 0, 0, 0);
                }
            }
            s8v hf[2];
            #pragma unroll
            for (int nt = 0; nt < 4; nt++) {
                #pragma unroll
                for (int r = 0; r < 4; r++) {
                    float hv = acc[nt][r] + bf2f((ushort_t)sgB[nt][r]) + bf2f((ushort_t)tgB[nt][r]);
                    hv = fmaxf(hv, 0.f);
                    hf[nt >> 1][((nt & 1) << 2) + r] = (short)f2bf(hv);
                }
            }
            f4 out[4];
            #pragma unroll
            for (int nt = 0; nt < 4; nt++) out[nt] = (f4){0.f, 0.f, 0.f, 0.f};
            #pragma unroll
            for (int nt = 0; nt < 4; nt++) {
                #pragma unroll
                for (int kt = 0; kt < 2; kt++) {
                    out[nt] = __builtin_amdgcn_mfma_f32_16x16x32_bf16(w1f[nt][kt], hf[kt], out[nt], 0, 0, 0);
                }
            }
            if (idxB < E) {
                #pragma unroll
                for (int nt = 0; nt < 4; nt++) out[nt] += b1v[nt];
                ushort_t* prow = out_p + (size_t)idxB * D;
                #pragma unroll
                for (int nt = 0; nt < 4; nt++) {
                    s4v ov;
                    #pragma unroll
                    for (int r = 0; r < 4; r++) ov[r] = (short)f2bf(out[nt][r]);
                    *(s4v*)(prow + 16 * nt + 4 * g) = ov;
                }
                if (MODE == 1) {
                    float* orow = out_e + (size_t)emB * D;
                    #pragma unroll
                    for (int nt = 0; nt < 4; nt++) *(f4*)&orow[16 * nt + 4 * g] = out[nt];
                }
            }
        }

        if (!more) break;
        t = tn; idxA = idxAn; idxB = idxBn;
        eaA0 = eaA0n; eaA1 = eaA1n; eaB0 = eaB0n; eaB1 = eaB1n;
        sA = sAn; dA = dAn; sB = sBn; dB = dBn; emA = emAn; emB = emBn;
    }
}

extern "C" void kernel_launch(void* const* d_in, const int* in_sizes, int n_in,
                              void* d_out, int out_size, void* d_ws, size_t ws_size,
                              hipStream_t stream) {
    const float* x0  = (const float*)d_in[0];
    const int*   ei  = (const int*)d_in[1];
    const float* ea0 = (const float*)d_in[2];
    const float* Wr  = (const float*)d_in[3];
    const float* Wn  = (const float*)d_in[4];
    const float* We  = (const float*)d_in[5];
    const float* b   = (const float*)d_in[6];
    const float* EWe = (const float*)d_in[7];
    const float* Ebe = (const float*)d_in[8];
    const float* EWs = (const float*)d_in[9];
    const float* Ebs = (const float*)d_in[10];
    const float* EWt = (const float*)d_in[11];
    const float* Ebt = (const float*)d_in[12];
    const float* EW1 = (const float*)d_in[13];
    const float* Eb1 = (const float*)d_in[14];

    const int N = in_sizes[0] / D;
    const int E = in_sizes[1] / 2;
    const int* src = ei;
    const int* dst = ei + E;

    char* ws = (char*)d_ws;
    size_t off = 0;
    auto alloc = [&](size_t bytes) {
        void* p = ws + off;
        off += (bytes + 255) & ~(size_t)255;
        return p;
    };
    int*      cntcur    = (int*)alloc((size_t)2 * N * 4);
    int*      cnt       = cntcur;
    int*      cursor    = cntcur + N;
    int*      row_start = (int*)alloc((size_t)(N + 1) * 4);
    int*      eids      = (int*)alloc((size_t)E * 4);
    int*      srcs      = (int*)alloc((size_t)E * 4);
    int*      pdst      = (int*)alloc((size_t)E * 4);
    int*      pos       = (int*)alloc((size_t)E * 4);
    float*    inv_deg   = (float*)alloc((size_t)N * 4);
    ushort_t* Sx        = (ushort_t*)alloc((size_t)N * D * 2);
    ushort_t* Se        = (ushort_t*)alloc((size_t)N * D * 2);
    ushort_t* xb0       = (ushort_t*)alloc((size_t)N * D * 2);
    ushort_t* xb1       = (ushort_t*)alloc((size_t)N * D * 2);
    ushort_t* sfb       = (ushort_t*)alloc((size_t)N * D * 2);
    ushort_t* tfb       = (ushort_t*)alloc((size_t)N * D * 2);
    s8v*      wbuf      = (s8v*)alloc((size_t)28 * 512 * 16);
    ushort_t* pea       = (ushort_t*)alloc((size_t)E * D * 2);

    float* outx  = (float*)d_out;
    float* outea = (float*)d_out + (size_t)N * D;

    hipMemsetAsync(cntcur, 0, (size_t)2 * N * 4, stream);
    k_count<<<(E + 255) / 256, 256, 0, stream>>>(dst, cnt, E);
    k_scan<<<1, 1024, 0, stream>>>(cnt, row_start, inv_deg, N);
    k_fill<<<(E + 255) / 256, 256, 0, stream>>>(src, dst, row_start, cursor,
                                                eids, srcs, pdst, pos, E);
    {
        int pblocks = (E * 8 + 255) / 256;
        int xblocks = (N * D / 8 + 255) / 256;
        k_permcvt<<<pblocks + xblocks, 256, 0, stream>>>(ea0, pos, pea, E, x0, xb0, N * D / 8, pblocks);
    }
    k_prepw<<<28, 64, 0, stream>>>(Wr, Wn, We, EWe, EW1, EWs, EWt, wbuf);

    dim3 b644(64, 4);
    const s8v* wbn0  = wbuf;               // conv layer 0: 6 sets
    const s8v* wbn1  = wbuf + 6 * 512;
    const s8v* wbn2  = wbuf + 12 * 512;
    const s8v* wbe0  = wbuf + 18 * 512;    // edge layer 0: 3 sets
    const s8v* wbe1  = wbuf + 21 * 512;
    const s8v* wbst0 = wbuf + 24 * 512;    // st layer 0: 2 sets
    const s8v* wbst1 = wbuf + 26 * 512;

    // ---- layer 0 ----
    k_agg_seq<<<(N + 3) / 4, b644, 0, stream>>>(xb0, pea, row_start, srcs, Sx, Se, N);
    k_node_mfma<1, 0><<<1024, 256, 0, stream>>>(xb0, Sx, Se, inv_deg, wbn0, b,
                                                wbst0, Ebs, Ebt, Ebe,
                                                nullptr, xb1, sfb, tfb, N);
    k_edge_mfma<0><<<2048, 256, 0, stream>>>(pea, srcs, pdst, eids, sfb, tfb,
                                             wbe0, Eb1, pea, nullptr, E);

    // ---- layer 1 ----
    k_agg_seq<<<(N + 3) / 4, b644, 0, stream>>>(xb1, pea, row_start, srcs, Sx, Se, N);
    k_node_mfma<1, 0><<<1024, 256, 0, stream>>>(xb1, Sx, Se, inv_deg, wbn1, b + D,
                                                wbst1, Ebs + D, Ebt + D, Ebe + D,
                                                nullptr, xb0, sfb, tfb, N);
    k_edge_mfma<1><<<2048, 256, 0, stream>>>(pea, srcs, pdst, eids, sfb, tfb,
                                             wbe1, Eb1 + D, pea, outea, E);

    // ---- layer 2 ----
    k_agg_seq<<<(N + 3) / 4, b644, 0, stream>>>(xb0, pea, row_start, srcs, Sx, Se, N);
    k_node_mfma<0, 1><<<1024, 256, 0, stream>>>(xb0, Sx, Se, inv_deg, wbn2, b + 2 * D,
                                                nullptr, nullptr, nullptr, nullptr,
                                                outx, nullptr, nullptr, nullptr, N);
}